// Round 1
// baseline (4967.210 us; speedup 1.0000x reference)
//
#include <hip/hip_runtime.h>

#define NN    100000   // nodes
#define NEDGE 100000   // edges per relation
#define NRELS 6
#define HIDD  256
#define NGR   128      // graphs

#define BM 64
#define BN 64
#define BK 16
#define LP 68          // padded LDS leading dim (16B-aligned rows: 68*4B = 272 = 17*16)

union F4 { float4 v; float f[4]; };

// h[n][0:128] = type_emb[x_type[n]], h[n][128:256] = sub_emb[x_sub[n]]
__global__ __launch_bounds__(256)
void embed_kernel(const int* __restrict__ xt, const int* __restrict__ xs,
                  const float* __restrict__ temb, const float* __restrict__ semb,
                  float* __restrict__ h)
{
    int n = blockIdx.x;
    int f = threadIdx.x;
    float v;
    if (f < 128) v = temb[xt[n] * 128 + f];
    else         v = semb[xs[n] * 128 + (f - 128)];
    h[(size_t)n * HIDD + f] = v;
}

// deg[t] = number of incoming edges over all relations (float)
__global__ __launch_bounds__(256)
void deg_kernel(const int* __restrict__ edges, float* __restrict__ deg)
{
    int i = blockIdx.x * 256 + threadIdx.x;
    if (i >= NRELS * NEDGE) return;
    int r = i / NEDGE;
    int e = i - r * NEDGE;
    int t = edges[r * (2 * NEDGE) + NEDGE + e];
    atomicAdd(&deg[t], 1.0f);
}

// Per relation r (blockIdx.z): C[e][:] = h[src[r,e]][:] @ W_rel[r]; atomicAdd into accum[tgt[r,e]][:]
__global__ __launch_bounds__(256)
void rel_gemm_kernel(const float* __restrict__ h, const float* __restrict__ Wrel,
                     const int* __restrict__ edges, float* __restrict__ accum)
{
    const int r = blockIdx.z;
    const float* __restrict__ W = Wrel + (size_t)r * HIDD * HIDD;
    const int* __restrict__ src = edges + (size_t)r * (2 * NEDGE);
    const int* __restrict__ tgt = src + NEDGE;

    const int m0 = blockIdx.x * BM;
    const int n0 = blockIdx.y * BN;

    __shared__ float As[BK][LP];   // As[k][m]
    __shared__ float Bs[BK][LP];   // Bs[k][n]
    __shared__ int   src_l[BM];
    __shared__ int   tgt_l[BM];

    const int tid = threadIdx.x;
    if (tid < BM) {
        int e = m0 + tid;
        int s = 0, t = 0;
        if (e < NEDGE) { s = src[e]; t = tgt[e]; }
        src_l[tid] = s; tgt_l[tid] = t;
    }
    __syncthreads();

    const int tx = tid & 15, ty = tid >> 4;
    const int tx4 = tx * 4, ty4 = ty * 4;
    // A loader: thread -> row am in tile, 4 contiguous k
    const int am = tid >> 2, ak4 = (tid & 3) * 4;
    // B loader: thread -> k-row bk, 4 contiguous n
    const int bk = tid >> 4, bn4 = (tid & 15) * 4;

    const float* __restrict__ arow = h + (size_t)src_l[am] * HIDD;

    float acc[4][4] = {};

    for (int k0 = 0; k0 < HIDD; k0 += BK) {
        float4 av = *(const float4*)(arow + k0 + ak4);
        float4 bv = *(const float4*)(W + (size_t)(k0 + bk) * HIDD + n0 + bn4);
        __syncthreads();
        As[ak4 + 0][am] = av.x;
        As[ak4 + 1][am] = av.y;
        As[ak4 + 2][am] = av.z;
        As[ak4 + 3][am] = av.w;
        *(float4*)&Bs[bk][bn4] = bv;
        __syncthreads();
#pragma unroll
        for (int k = 0; k < BK; ++k) {
            F4 a, b;
            a.v = *(const float4*)&As[k][ty4];
            b.v = *(const float4*)&Bs[k][tx4];
#pragma unroll
            for (int i = 0; i < 4; ++i)
#pragma unroll
                for (int j = 0; j < 4; ++j)
                    acc[i][j] = fmaf(a.f[i], b.f[j], acc[i][j]);
        }
    }

#pragma unroll
    for (int i = 0; i < 4; ++i) {
        int m = ty4 + i;
        int e = m0 + m;
        if (e < NEDGE) {
            float* dst = accum + (size_t)tgt_l[m] * HIDD + n0 + tx4;
#pragma unroll
            for (int j = 0; j < 4; ++j) atomicAdd(dst + j, acc[i][j]);
        }
    }
}

// outb[row][:] = relu(outb[row][:]/max(deg,1) + h[row][:] @ Wself + b)   (in-place on accum)
__global__ __launch_bounds__(256)
void self_gemm_kernel(const float* __restrict__ h, const float* __restrict__ Wself,
                      const float* __restrict__ bias, const float* __restrict__ deg,
                      float* __restrict__ outb)
{
    const int m0 = blockIdx.x * BM;
    const int n0 = blockIdx.y * BN;

    __shared__ float As[BK][LP];
    __shared__ float Bs[BK][LP];

    const int tid = threadIdx.x;
    const int tx = tid & 15, ty = tid >> 4;
    const int tx4 = tx * 4, ty4 = ty * 4;
    const int am = tid >> 2, ak4 = (tid & 3) * 4;
    const int bk = tid >> 4, bn4 = (tid & 15) * 4;

    int arow_idx = m0 + am;
    if (arow_idx >= NN) arow_idx = NN - 1;
    const float* __restrict__ arow = h + (size_t)arow_idx * HIDD;

    float acc[4][4] = {};

    for (int k0 = 0; k0 < HIDD; k0 += BK) {
        float4 av = *(const float4*)(arow + k0 + ak4);
        float4 bv = *(const float4*)(Wself + (size_t)(k0 + bk) * HIDD + n0 + bn4);
        __syncthreads();
        As[ak4 + 0][am] = av.x;
        As[ak4 + 1][am] = av.y;
        As[ak4 + 2][am] = av.z;
        As[ak4 + 3][am] = av.w;
        *(float4*)&Bs[bk][bn4] = bv;
        __syncthreads();
#pragma unroll
        for (int k = 0; k < BK; ++k) {
            F4 a, b;
            a.v = *(const float4*)&As[k][ty4];
            b.v = *(const float4*)&Bs[k][tx4];
#pragma unroll
            for (int i = 0; i < 4; ++i)
#pragma unroll
                for (int j = 0; j < 4; ++j)
                    acc[i][j] = fmaf(a.f[i], b.f[j], acc[i][j]);
        }
    }

#pragma unroll
    for (int i = 0; i < 4; ++i) {
        int row = m0 + ty4 + i;
        if (row < NN) {
            float d = fmaxf(deg[row], 1.0f);
            float* po = outb + (size_t)row * HIDD + n0 + tx4;
#pragma unroll
            for (int j = 0; j < 4; ++j) {
                float v = po[j] / d + acc[i][j] + bias[n0 + tx4 + j];
                po[j] = fmaxf(v, 0.0f);
            }
        }
    }
}

// Segmented mean-pool numerator + counts. batch_ids sorted -> per-block run-length
// reduction, atomics only at run boundaries.
#define PCHUNK 512
__global__ __launch_bounds__(256)
void pool_kernel(const float* __restrict__ h, const int* __restrict__ batch_ids,
                 float* __restrict__ pooled, float* __restrict__ cnt)
{
    const int n0 = blockIdx.x * PCHUNK;
    const int f = threadIdx.x;
    __shared__ int bid_l[PCHUNK];
    for (int i = f; i < PCHUNK; i += 256) {
        int n = n0 + i;
        bid_l[i] = (n < NN) ? batch_ids[n] : -1;
    }
    __syncthreads();
    const int nEnd = (NN - n0 < PCHUNK) ? (NN - n0) : PCHUNK;
    float s = 0.0f;
    int g = bid_l[0];
    int run = 0;
    for (int i = 0; i < nEnd; ++i) {
        int bg = bid_l[i];
        if (bg != g) {  // uniform across block
            atomicAdd(&pooled[g * HIDD + f], s);
            if (f == 0) atomicAdd(&cnt[g], (float)run);
            s = 0.0f; run = 0; g = bg;
        }
        s += h[(size_t)(n0 + i) * HIDD + f];
        run++;
    }
    if (run > 0) {
        atomicAdd(&pooled[g * HIDD + f], s);
        if (f == 0) atomicAdd(&cnt[g], (float)run);
    }
}

// out[g][:] = relu(pooled[g]/cnt[g] @ pW1 + pb1) @ pW2 + pb2   (one block per graph)
__global__ __launch_bounds__(256)
void mlp_kernel(const float* __restrict__ pooled, const float* __restrict__ cnt,
                const float* __restrict__ pW1, const float* __restrict__ pb1,
                const float* __restrict__ pW2, const float* __restrict__ pb2,
                float* __restrict__ out)
{
    const int g = blockIdx.x;
    const int d = threadIdx.x;
    __shared__ float pn[HIDD];
    __shared__ float mid[HIDD];
    float c = fmaxf(cnt[g], 1.0f);
    pn[d] = pooled[g * HIDD + d] / c;
    __syncthreads();
    float s = pb1[d];
    for (int k = 0; k < HIDD; ++k) s = fmaf(pn[k], pW1[k * HIDD + d], s);
    mid[d] = fmaxf(s, 0.0f);
    __syncthreads();
    float s2 = pb2[d];
    for (int k = 0; k < HIDD; ++k) s2 = fmaf(mid[k], pW2[k * HIDD + d], s2);
    out[g * HIDD + d] = s2;
}

extern "C" void kernel_launch(void* const* d_in, const int* in_sizes, int n_in,
                              void* d_out, int out_size, void* d_ws, size_t ws_size,
                              hipStream_t stream)
{
    const int*   x_type    = (const int*)d_in[0];
    const int*   x_sub     = (const int*)d_in[1];
    const int*   edges     = (const int*)d_in[2];
    const int*   batch_ids = (const int*)d_in[3];
    // d_in[4] = n_graphs scalar (unused; NGR compile-time)
    const float* type_emb  = (const float*)d_in[5];
    const float* sub_emb   = (const float*)d_in[6];
    const float* W_rel0    = (const float*)d_in[7];
    const float* W_self0   = (const float*)d_in[8];
    const float* b0        = (const float*)d_in[9];
    const float* W_rel1    = (const float*)d_in[10];
    const float* W_self1   = (const float*)d_in[11];
    const float* b1        = (const float*)d_in[12];
    const float* pW1       = (const float*)d_in[13];
    const float* pb1       = (const float*)d_in[14];
    const float* pW2       = (const float*)d_in[15];
    const float* pb2       = (const float*)d_in[16];
    float* out = (float*)d_out;

    float* hA     = (float*)d_ws;                      // N*H
    float* hB     = hA + (size_t)NN * HIDD;            // N*H
    float* deg    = hB + (size_t)NN * HIDD;            // N
    float* pooled = deg + NN;                          // NGR*H
    float* cnt    = pooled + (size_t)NGR * HIDD;       // NGR

    // zero deg + pooled + cnt (contiguous)
    hipMemsetAsync(deg, 0, (size_t)(NN + NGR * HIDD + NGR) * sizeof(float), stream);

    embed_kernel<<<NN, 256, 0, stream>>>(x_type, x_sub, type_emb, sub_emb, hA);
    deg_kernel<<<(NRELS * NEDGE + 255) / 256, 256, 0, stream>>>(edges, deg);

    dim3 relgrid((NEDGE + BM - 1) / BM, HIDD / BN, NRELS);
    dim3 selfgrid((NN + BM - 1) / BM, HIDD / BN);

    // Layer 0: hA -> hB
    hipMemsetAsync(hB, 0, (size_t)NN * HIDD * sizeof(float), stream);
    rel_gemm_kernel<<<relgrid, 256, 0, stream>>>(hA, W_rel0, edges, hB);
    self_gemm_kernel<<<selfgrid, 256, 0, stream>>>(hA, W_self0, b0, deg, hB);

    // Layer 1: hB -> hA
    hipMemsetAsync(hA, 0, (size_t)NN * HIDD * sizeof(float), stream);
    rel_gemm_kernel<<<relgrid, 256, 0, stream>>>(hB, W_rel1, edges, hA);
    self_gemm_kernel<<<selfgrid, 256, 0, stream>>>(hB, W_self1, b1, deg, hA);

    pool_kernel<<<(NN + PCHUNK - 1) / PCHUNK, 256, 0, stream>>>(hA, batch_ids, pooled, cnt);
    mlp_kernel<<<NGR, 256, 0, stream>>>(pooled, cnt, pW1, pb1, pW2, pb2, out);
}

// Round 2
// 1454.907 us; speedup vs baseline: 3.4141x; 3.4141x over previous
//
#include <hip/hip_runtime.h>

#define NN    100000   // nodes
#define NEDGE 100000   // edges per relation
#define NRELS 6
#define HIDD  256
#define NGR   128      // graphs

// MFMA GEMM tiling
#define BM 128
#define BN 64
#define BK 32

typedef __bf16 bf16;
typedef __bf16 bf16x8 __attribute__((ext_vector_type(8)));
typedef float  f32x4  __attribute__((ext_vector_type(4)));

// ---------------- embed: h_bf[n][0:128]=type_emb[xt], [128:256]=sub_emb[xs] ----------------
__global__ __launch_bounds__(256)
void embed_kernel(const int* __restrict__ xt, const int* __restrict__ xs,
                  const float* __restrict__ temb, const float* __restrict__ semb,
                  bf16* __restrict__ h)
{
    int n = blockIdx.x;
    int f = threadIdx.x;
    float v;
    if (f < 128) v = temb[xt[n] * 128 + f];
    else         v = semb[xs[n] * 128 + (f - 128)];
    h[(size_t)n * HIDD + f] = (bf16)v;
}

// ---------------- deg[t] = total incoming degree over all relations ----------------
__global__ __launch_bounds__(256)
void deg_kernel(const int* __restrict__ edges, float* __restrict__ deg)
{
    int i = blockIdx.x * 256 + threadIdx.x;
    if (i >= NRELS * NEDGE) return;
    int r = i / NEDGE;
    int e = i - r * NEDGE;
    int t = edges[r * (2 * NEDGE) + NEDGE + e];
    atomicAdd(&deg[t], 1.0f);
}

// ---------------- W[k][n] fp32 -> Wt[n][k] bf16 (nmats matrices of 256x256) ----------------
__global__ __launch_bounds__(256)
void transpose_w(const float* __restrict__ W, bf16* __restrict__ Wt)
{
    int idx = blockIdx.x * 256 + threadIdx.x;   // grid sized exactly: nmats*65536/256
    int r = idx >> 16;
    int n = (idx >> 8) & 255;
    int k = idx & 255;
    Wt[((size_t)r << 16) + (n << 8) + k] = (bf16)W[((size_t)r << 16) + (k << 8) + n];
}

// ---------------- rel GEMM: accum[tgt[e]] += (h[src[e]] @ W_r), MFMA bf16 ----------------
// grid: (ceil(NEDGE/BM), HIDD/BN, NRELS), block 256 (4 waves; wave w -> rows w*32..w*32+31)
__global__ __launch_bounds__(256, 2)
void rel_gemm_mfma(const bf16* __restrict__ hbf, const bf16* __restrict__ Wt,
                   const int* __restrict__ edges, float* __restrict__ accum)
{
    const int r = blockIdx.z;
    const bf16* __restrict__ W = Wt + ((size_t)r << 16);          // Wt[n][k]
    const int* __restrict__ src = edges + (size_t)r * 2 * NEDGE;
    const int* __restrict__ tgt = src + NEDGE;
    const int m0 = blockIdx.x * BM;
    const int n0 = blockIdx.y * BN;

    __shared__ __align__(16) bf16 As[BM * BK];   // [row][k], 64B rows
    __shared__ __align__(16) bf16 Bs[BN * BK];   // [n][k],  64B rows
    __shared__ int src_l[BM];
    __shared__ int tgt_l[BM];

    const int tid = threadIdx.x;
    if (tid < BM) {
        int e = m0 + tid;
        int s = 0, t = -1;
        if (e < NEDGE) { s = src[e]; t = tgt[e]; }
        src_l[tid] = s; tgt_l[tid] = t;
    }
    __syncthreads();

    const int lane = tid & 63;
    const int w = tid >> 6;

    // staging: thread -> (row = tid>>2, 8 bf16 at col (tid&3)*8); A needs 2 passes (128 rows)
    const int arow0 = tid >> 2;
    const int acol  = (tid & 3) * 8;
    const size_t ga0 = (size_t)src_l[arow0] * HIDD + acol;
    const size_t ga1 = (size_t)src_l[arow0 + 64] * HIDD + acol;
    const bf16* __restrict__ bsrc = W + (size_t)(n0 + arow0) * HIDD + acol;

    // frag addresses
    const int fm = lane & 15;            // row/col within 16x16
    const int kq = (lane >> 4) * 8;      // k element offset

    f32x4 acc[2][4] = {};

    for (int k0 = 0; k0 < HIDD; k0 += BK) {
        uint4 a0 = *(const uint4*)(hbf + ga0 + k0);
        uint4 a1 = *(const uint4*)(hbf + ga1 + k0);
        uint4 b0 = *(const uint4*)(bsrc + k0);
        __syncthreads();
        *(uint4*)&As[arow0 * BK + acol]        = a0;
        *(uint4*)&As[(arow0 + 64) * BK + acol] = a1;
        *(uint4*)&Bs[arow0 * BK + acol]        = b0;
        __syncthreads();

        bf16x8 af[2], bfr[4];
        af[0] = *(const bf16x8*)&As[(w * 32 + fm) * BK + kq];
        af[1] = *(const bf16x8*)&As[(w * 32 + 16 + fm) * BK + kq];
#pragma unroll
        for (int j = 0; j < 4; ++j)
            bfr[j] = *(const bf16x8*)&Bs[(j * 16 + fm) * BK + kq];
#pragma unroll
        for (int i = 0; i < 2; ++i)
#pragma unroll
            for (int j = 0; j < 4; ++j)
                acc[i][j] = __builtin_amdgcn_mfma_f32_16x16x32_bf16(af[i], bfr[j], acc[i][j], 0, 0, 0);
    }

    // epilogue: C row = w*32 + i*16 + (lane>>4)*4 + reg, col = j*16 + (lane&15)
    const int rbase = (lane >> 4) * 4;
#pragma unroll
    for (int i = 0; i < 2; ++i) {
#pragma unroll
        for (int reg = 0; reg < 4; ++reg) {
            int mrow = w * 32 + i * 16 + rbase + reg;
            int t = tgt_l[mrow];
            if (t >= 0) {
                float* dst = accum + (size_t)t * HIDD + n0 + fm;
#pragma unroll
                for (int j = 0; j < 4; ++j)
                    atomicAdd(dst + j * 16, acc[i][j][reg]);
            }
        }
    }
}

// ---------------- self GEMM + normalize + bias + relu -> out_bf (bf16) ----------------
// out[row] = relu(accum[row]/max(deg,1) + h[row] @ W_self + b)
__global__ __launch_bounds__(256, 2)
void self_gemm_mfma(const bf16* __restrict__ hbf, const bf16* __restrict__ Wt,
                    const float* __restrict__ bias, const float* __restrict__ deg,
                    const float* __restrict__ accum, bf16* __restrict__ outbf)
{
    const int m0 = blockIdx.x * BM;
    const int n0 = blockIdx.y * BN;

    __shared__ __align__(16) bf16 As[BM * BK];
    __shared__ __align__(16) bf16 Bs[BN * BK];

    const int tid = threadIdx.x;
    const int lane = tid & 63;
    const int w = tid >> 6;

    const int arow0 = tid >> 2;
    const int acol  = (tid & 3) * 8;
    int r0 = m0 + arow0;      if (r0 >= NN) r0 = NN - 1;
    int r1 = m0 + arow0 + 64; if (r1 >= NN) r1 = NN - 1;
    const size_t ga0 = (size_t)r0 * HIDD + acol;
    const size_t ga1 = (size_t)r1 * HIDD + acol;
    const bf16* __restrict__ bsrc = Wt + (size_t)(n0 + arow0) * HIDD + acol;

    const int fm = lane & 15;
    const int kq = (lane >> 4) * 8;

    f32x4 acc[2][4] = {};

    for (int k0 = 0; k0 < HIDD; k0 += BK) {
        uint4 a0 = *(const uint4*)(hbf + ga0 + k0);
        uint4 a1 = *(const uint4*)(hbf + ga1 + k0);
        uint4 b0 = *(const uint4*)(bsrc + k0);
        __syncthreads();
        *(uint4*)&As[arow0 * BK + acol]        = a0;
        *(uint4*)&As[(arow0 + 64) * BK + acol] = a1;
        *(uint4*)&Bs[arow0 * BK + acol]        = b0;
        __syncthreads();

        bf16x8 af[2], bfr[4];
        af[0] = *(const bf16x8*)&As[(w * 32 + fm) * BK + kq];
        af[1] = *(const bf16x8*)&As[(w * 32 + 16 + fm) * BK + kq];
#pragma unroll
        for (int j = 0; j < 4; ++j)
            bfr[j] = *(const bf16x8*)&Bs[(j * 16 + fm) * BK + kq];
#pragma unroll
        for (int i = 0; i < 2; ++i)
#pragma unroll
            for (int j = 0; j < 4; ++j)
                acc[i][j] = __builtin_amdgcn_mfma_f32_16x16x32_bf16(af[i], bfr[j], acc[i][j], 0, 0, 0);
    }

    const int rbase = (lane >> 4) * 4;
#pragma unroll
    for (int i = 0; i < 2; ++i) {
#pragma unroll
        for (int reg = 0; reg < 4; ++reg) {
            int row = m0 + w * 32 + i * 16 + rbase + reg;
            if (row < NN) {
                float d = fmaxf(deg[row], 1.0f);
                float inv = 1.0f / d;
                const float* pa = accum + (size_t)row * HIDD + n0 + fm;
                bf16* po = outbf + (size_t)row * HIDD + n0 + fm;
#pragma unroll
                for (int j = 0; j < 4; ++j) {
                    float v = pa[j * 16] * inv + acc[i][j][reg] + bias[n0 + fm + j * 16];
                    po[j * 16] = (bf16)fmaxf(v, 0.0f);
                }
            }
        }
    }
}

// ---------------- segmented mean-pool (batch_ids sorted) ----------------
#define PCHUNK 512
__global__ __launch_bounds__(256)
void pool_kernel(const bf16* __restrict__ h, const int* __restrict__ batch_ids,
                 float* __restrict__ pooled, float* __restrict__ cnt)
{
    const int n0 = blockIdx.x * PCHUNK;
    const int f = threadIdx.x;
    __shared__ int bid_l[PCHUNK];
    for (int i = f; i < PCHUNK; i += 256) {
        int n = n0 + i;
        bid_l[i] = (n < NN) ? batch_ids[n] : -1;
    }
    __syncthreads();
    const int nEnd = (NN - n0 < PCHUNK) ? (NN - n0) : PCHUNK;
    float s = 0.0f;
    int g = bid_l[0];
    int run = 0;
    for (int i = 0; i < nEnd; ++i) {
        int bg = bid_l[i];
        if (bg != g) {
            atomicAdd(&pooled[g * HIDD + f], s);
            if (f == 0) atomicAdd(&cnt[g], (float)run);
            s = 0.0f; run = 0; g = bg;
        }
        s += (float)h[(size_t)(n0 + i) * HIDD + f];
        run++;
    }
    if (run > 0) {
        atomicAdd(&pooled[g * HIDD + f], s);
        if (f == 0) atomicAdd(&cnt[g], (float)run);
    }
}

// ---------------- MLP head (fp32, one block per graph) ----------------
__global__ __launch_bounds__(256)
void mlp_kernel(const float* __restrict__ pooled, const float* __restrict__ cnt,
                const float* __restrict__ pW1, const float* __restrict__ pb1,
                const float* __restrict__ pW2, const float* __restrict__ pb2,
                float* __restrict__ out)
{
    const int g = blockIdx.x;
    const int d = threadIdx.x;
    __shared__ float pn[HIDD];
    __shared__ float mid[HIDD];
    float c = fmaxf(cnt[g], 1.0f);
    pn[d] = pooled[g * HIDD + d] / c;
    __syncthreads();
    float s = pb1[d];
    for (int k = 0; k < HIDD; ++k) s = fmaf(pn[k], pW1[k * HIDD + d], s);
    mid[d] = fmaxf(s, 0.0f);
    __syncthreads();
    float s2 = pb2[d];
    for (int k = 0; k < HIDD; ++k) s2 = fmaf(mid[k], pW2[k * HIDD + d], s2);
    out[g * HIDD + d] = s2;
}

extern "C" void kernel_launch(void* const* d_in, const int* in_sizes, int n_in,
                              void* d_out, int out_size, void* d_ws, size_t ws_size,
                              hipStream_t stream)
{
    const int*   x_type    = (const int*)d_in[0];
    const int*   x_sub     = (const int*)d_in[1];
    const int*   edges     = (const int*)d_in[2];
    const int*   batch_ids = (const int*)d_in[3];
    const float* type_emb  = (const float*)d_in[5];
    const float* sub_emb   = (const float*)d_in[6];
    const float* W_rel0    = (const float*)d_in[7];
    const float* W_self0   = (const float*)d_in[8];
    const float* b0        = (const float*)d_in[9];
    const float* W_rel1    = (const float*)d_in[10];
    const float* W_self1   = (const float*)d_in[11];
    const float* b1        = (const float*)d_in[12];
    const float* pW1       = (const float*)d_in[13];
    const float* pb1       = (const float*)d_in[14];
    const float* pW2       = (const float*)d_in[15];
    const float* pb2       = (const float*)d_in[16];
    float* out = (float*)d_out;

    // workspace carve-up
    char* p = (char*)d_ws;
    float* accum   = (float*)p;  p += (size_t)NN * HIDD * sizeof(float);   // 102.4 MB
    bf16*  hA      = (bf16*)p;   p += (size_t)NN * HIDD * sizeof(bf16);    // 51.2 MB
    bf16*  hB      = (bf16*)p;   p += (size_t)NN * HIDD * sizeof(bf16);    // 51.2 MB
    float* deg     = (float*)p;  p += (size_t)NN * sizeof(float);
    float* pooled  = (float*)p;  p += (size_t)NGR * HIDD * sizeof(float);
    float* cnt     = (float*)p;  p += (size_t)NGR * sizeof(float);
    bf16*  WtR0    = (bf16*)p;   p += (size_t)NRELS * HIDD * HIDD * sizeof(bf16);
    bf16*  WtR1    = (bf16*)p;   p += (size_t)NRELS * HIDD * HIDD * sizeof(bf16);
    bf16*  WtS0    = (bf16*)p;   p += (size_t)HIDD * HIDD * sizeof(bf16);
    bf16*  WtS1    = (bf16*)p;   p += (size_t)HIDD * HIDD * sizeof(bf16);

    // zero deg + pooled + cnt (contiguous block)
    hipMemsetAsync(deg, 0, (size_t)(NN + NGR * HIDD + NGR) * sizeof(float), stream);

    embed_kernel<<<NN, 256, 0, stream>>>(x_type, x_sub, type_emb, sub_emb, hA);
    deg_kernel<<<(NRELS * NEDGE + 255) / 256, 256, 0, stream>>>(edges, deg);

    transpose_w<<<NRELS * 256, 256, 0, stream>>>(W_rel0, WtR0);
    transpose_w<<<NRELS * 256, 256, 0, stream>>>(W_rel1, WtR1);
    transpose_w<<<256, 256, 0, stream>>>(W_self0, WtS0);
    transpose_w<<<256, 256, 0, stream>>>(W_self1, WtS1);

    dim3 relgrid((NEDGE + BM - 1) / BM, HIDD / BN, NRELS);
    dim3 selfgrid((NN + BM - 1) / BM, HIDD / BN);

    // Layer 0: hA -> hB
    hipMemsetAsync(accum, 0, (size_t)NN * HIDD * sizeof(float), stream);
    rel_gemm_mfma<<<relgrid, 256, 0, stream>>>(hA, WtR0, edges, accum);
    self_gemm_mfma<<<selfgrid, 256, 0, stream>>>(hA, WtS0, b0, deg, accum, hB);

    // Layer 1: hB -> hA
    hipMemsetAsync(accum, 0, (size_t)NN * HIDD * sizeof(float), stream);
    rel_gemm_mfma<<<relgrid, 256, 0, stream>>>(hB, WtR1, edges, accum);
    self_gemm_mfma<<<selfgrid, 256, 0, stream>>>(hB, WtS1, b1, deg, accum, hA);

    pool_kernel<<<(NN + PCHUNK - 1) / PCHUNK, 256, 0, stream>>>(hA, batch_ids, pooled, cnt);
    mlp_kernel<<<NGR, 256, 0, stream>>>(pooled, cnt, pW1, pb1, pW2, pb2, out);
}